// Round 1
// baseline (25471.536 us; speedup 1.0000x reference)
//
#include <hip/hip_runtime.h>

// DARTS RNN cell, T=1024 steps, B=64, NHID=NINP=256.
// Decomposition: 16 workgroups x 256 threads. wg n owns state columns
// [16n,16n+16) -> weight cols {16n..16n+16} (c-half) and {256+16n..} (h-half).
// Genotype weights (8 x [256x32] bf16) stationary in LDS in MFMA B-fragment
// order (128KB); W0 slice ([512x32]) in VGPRs. Per step: 7 dependent slots,
// each ending in a device-scope barrier; state slices exchanged via global
// bf16 A-fragment buffers in d_ws.

#define TT 1024
#define NWG 16
#define NBAR (TT * 7)

typedef __attribute__((ext_vector_type(8))) short bf16x8;
typedef __attribute__((ext_vector_type(4))) float f32x4;

__device__ __forceinline__ unsigned short f2bf(float f) {
  unsigned u = __builtin_bit_cast(unsigned, f);
  u += 0x7FFFu + ((u >> 16) & 1u);   // round-to-nearest-even
  return (unsigned short)(u >> 16);
}
__device__ __forceinline__ float sigm(float c) { return 1.0f / (1.0f + __expf(-c)); }
__device__ __forceinline__ float tanh_f(float h) {
  float e = __expf(2.0f * h);        // inf-safe: (1 - 2/(e+1)) -> +/-1
  return 1.0f - 2.0f / (e + 1.0f);
}

// Init: zero barrier counters; convert initial hidden -> bf16 A-fragment buffer.
__global__ void darts_init(const float* __restrict__ hid,
                           unsigned short* __restrict__ sf,
                           unsigned* __restrict__ cnt) {
  int tid = blockIdx.x * 256 + threadIdx.x;  // 2048 threads
  for (int i = tid; i < NBAR; i += 2048) cnt[i] = 0;
  int lane = tid & 63, mt = (tid >> 6) & 3, kc = tid >> 8;
  const float* ph = hid + (mt * 16 + (lane & 15)) * 256 + kc * 32 + (lane >> 4) * 8;
  bf16x8 v;
#pragma unroll
  for (int e = 0; e < 8; ++e) v[e] = (short)f2bf(ph[e]);
  *(bf16x8*)(sf + 6 * 16384 + tid * 8) = v;  // tid == ((kc*4+mt)*64+lane)
}

__global__ void __launch_bounds__(256, 1) darts_main(
    const float* __restrict__ x, const float* __restrict__ hid,
    const float* __restrict__ W0g, const float* __restrict__ Wsg,
    float* __restrict__ out,
    unsigned short* __restrict__ sf, unsigned* __restrict__ cnt) {
  extern __shared__ char sm[];
  const int wg = blockIdx.x, tid = threadIdx.x;
  const int wv = tid >> 6;           // wave id = M-tile (16 batch rows each)
  const int lane = tid & 63;
  const int lhi = lane >> 4, llo = lane & 15;

  // ---- stage genotype weights into LDS, fragment-major ----
  // layout: [gi(8)][n(2)][kc(8)][lane(64)][8 bf16]; flat == linear index
  for (int c = 0; c < 32; ++c) {
    int flat = tid + 256 * c;
    int fl = flat & 63, kc = (flat >> 6) & 7, n = (flat >> 9) & 1, gi = flat >> 10;
    int col = n * 256 + wg * 16 + (fl & 15);
    int kb = kc * 32 + (fl >> 4) * 8;
    bf16x8 v;
#pragma unroll
    for (int e = 0; e < 8; ++e) v[e] = (short)f2bf(Wsg[(gi * 256 + kb + e) * 512 + col]);
    *(bf16x8*)(&sm[flat * 16]) = v;
  }

  // ---- W0 B-fragments (K=512 -> 16 k-chunks) into VGPRs ----
  bf16x8 w0c[16], w0h[16];
#pragma unroll
  for (int kc = 0; kc < 16; ++kc) {
    int kb = kc * 32 + lhi * 8;
    bf16x8 vc, vh;
#pragma unroll
    for (int e = 0; e < 8; ++e) {
      vc[e] = (short)f2bf(W0g[(kb + e) * 512 + wg * 16 + llo]);
      vh[e] = (short)f2bf(W0g[(kb + e) * 512 + 256 + wg * 16 + llo]);
    }
    w0c[kc] = vc; w0h[kc] = vh;
  }

  // this thread owns (row = wv*16 + lhi*4 + r, local col = llo) for r=0..3
  float hprev[4];
  float st[9][4];
#pragma unroll
  for (int r = 0; r < 4; ++r)
    hprev[r] = hid[(wv * 16 + lhi * 4 + r) * 256 + wg * 16 + llo];

  __syncthreads();

  unsigned short* sfh = sf + 6 * 16384;
  const int colg = wg * 16 + llo;
  const int kcw = wg >> 1;                     // k-chunk of our columns
  const int g2 = (wg & 1) * 2 + (llo >> 3);    // lane-group within k-chunk
  const int eo = llo & 7;

#define GBAR(IDX) do { \
    __syncthreads(); \
    if (tid == 0) __hip_atomic_fetch_add(&cnt[IDX], 1u, __ATOMIC_RELEASE, __HIP_MEMORY_SCOPE_AGENT); \
    while (__hip_atomic_load(&cnt[IDX], __ATOMIC_RELAXED, __HIP_MEMORY_SCOPE_AGENT) < (unsigned)NWG) {} \
    __builtin_amdgcn_fence(__ATOMIC_ACQUIRE, "agent"); \
  } while (0)

#define LOADA(BUF) do { _Pragma("unroll") \
    for (int kc = 0; kc < 8; ++kc) \
      a[kc] = *(const bf16x8*)((BUF) + ((kc * 4 + wv) * 64 + lane) * 8); \
  } while (0)

#define MM(GI, AC, AH) do { _Pragma("unroll") \
    for (int kc = 0; kc < 8; ++kc) { \
      bf16x8 bc = *(const bf16x8*)(&sm[((((GI) * 2 + 0) * 8 + kc) * 64 + lane) * 16]); \
      bf16x8 bh = *(const bf16x8*)(&sm[((((GI) * 2 + 1) * 8 + kc) * 64 + lane) * 16]); \
      AC = __builtin_amdgcn_mfma_f32_16x16x32_bf16(a[kc], bc, AC, 0, 0, 0); \
      AH = __builtin_amdgcn_mfma_f32_16x16x32_bf16(a[kc], bh, AH, 0, 0, 0); \
    } } while (0)

#define UPD(SI, PR, ACT, AC, AH) do { _Pragma("unroll") \
    for (int r = 0; r < 4; ++r) { \
      float g = sigm((AC)[r]); float hh = (AH)[r]; \
      float av = (ACT) == 0 ? fmaxf(hh, 0.0f) : ((ACT) == 1 ? tanh_f(hh) : hh); \
      st[SI][r] = st[PR][r] + g * (av - st[PR][r]); \
    } } while (0)

#define STOREF(BUF, SI) do { _Pragma("unroll") \
    for (int r = 0; r < 4; ++r) { \
      int lp = g2 * 16 + lhi * 4 + r; \
      (BUF)[((kcw * 4 + wv) * 64 + lp) * 8 + eo] = f2bf(st[SI][r]); \
    } } while (0)

#pragma clang loop unroll(disable)
  for (int t = 0; t < TT; ++t) {
    // ---- slot A: s0 from xh @ W0 ----
    {
      bf16x8 a16[16];
#pragma unroll
      for (int kc = 0; kc < 8; ++kc) {
        const float* px = x + ((t * 64 + wv * 16 + llo) * 256 + kc * 32 + lhi * 8);
        bf16x8 v;
#pragma unroll
        for (int e = 0; e < 8; ++e) v[e] = (short)f2bf(px[e]);
        a16[kc] = v;
      }
#pragma unroll
      for (int kc = 0; kc < 8; ++kc)
        a16[8 + kc] = *(const bf16x8*)(sfh + ((kc * 4 + wv) * 64 + lane) * 8);
      f32x4 c0 = {0, 0, 0, 0}, h0 = {0, 0, 0, 0};
#pragma unroll
      for (int kc = 0; kc < 16; ++kc) {
        c0 = __builtin_amdgcn_mfma_f32_16x16x32_bf16(a16[kc], w0c[kc], c0, 0, 0, 0);
        h0 = __builtin_amdgcn_mfma_f32_16x16x32_bf16(a16[kc], w0h[kc], h0, 0, 0, 0);
      }
#pragma unroll
      for (int r = 0; r < 4; ++r) {
        float g = sigm(c0[r]);
        float th = tanh_f(h0[r]);
        st[0][r] = hprev[r] + g * (th - hprev[r]);
      }
      STOREF(sf + 0 * 16384, 0);
    }
    GBAR(t * 7 + 0);

    bf16x8 a[8];
    // ---- slot B: s1 = geno0(relu, pred s0) ----
    {
      LOADA(sf + 0 * 16384);
      f32x4 ac = {0, 0, 0, 0}, ah = {0, 0, 0, 0};
      MM(0, ac, ah);
      UPD(1, 0, 0, ac, ah);
      STOREF(sf + 1 * 16384, 1);
    }
    GBAR(t * 7 + 1);
    // ---- slot C: s2 (geno1), s6 (geno5, identity), s8 (geno7) — all pred s1 ----
    {
      LOADA(sf + 1 * 16384);
      f32x4 c2 = {0,0,0,0}, h2 = {0,0,0,0}, c6 = {0,0,0,0}, h6 = {0,0,0,0}, c8 = {0,0,0,0}, h8 = {0,0,0,0};
      MM(1, c2, h2); MM(5, c6, h6); MM(7, c8, h8);
      UPD(2, 1, 0, c2, h2);
      UPD(6, 1, 2, c6, h6);
      UPD(8, 1, 0, c8, h8);
      STOREF(sf + 2 * 16384, 2);
    }
    GBAR(t * 7 + 2);
    // ---- slot D: s3 = geno2(tanh, pred s2) ----
    {
      LOADA(sf + 2 * 16384);
      f32x4 ac = {0, 0, 0, 0}, ah = {0, 0, 0, 0};
      MM(2, ac, ah);
      UPD(3, 2, 1, ac, ah);
      STOREF(sf + 3 * 16384, 3);
    }
    GBAR(t * 7 + 3);
    // ---- slot E: s4 = geno3(relu, pred s3) ----
    {
      LOADA(sf + 3 * 16384);
      f32x4 ac = {0, 0, 0, 0}, ah = {0, 0, 0, 0};
      MM(3, ac, ah);
      UPD(4, 3, 0, ac, ah);
      STOREF(sf + 4 * 16384, 4);
    }
    GBAR(t * 7 + 4);
    // ---- slot F: s5 = geno4(relu, pred s4) ----
    {
      LOADA(sf + 4 * 16384);
      f32x4 ac = {0, 0, 0, 0}, ah = {0, 0, 0, 0};
      MM(4, ac, ah);
      UPD(5, 4, 0, ac, ah);
      STOREF(sf + 5 * 16384, 5);
    }
    GBAR(t * 7 + 5);
    // ---- slot G: s7 = geno6(relu, pred s5); h = mean(s1..s8) ----
    {
      LOADA(sf + 5 * 16384);
      f32x4 ac = {0, 0, 0, 0}, ah = {0, 0, 0, 0};
      MM(6, ac, ah);
      UPD(7, 5, 0, ac, ah);
      float hv[4];
#pragma unroll
      for (int r = 0; r < 4; ++r) {
        hv[r] = (st[1][r] + st[2][r] + st[3][r] + st[4][r] +
                 st[5][r] + st[6][r] + st[7][r] + st[8][r]) * 0.125f;
        hprev[r] = hv[r];
      }
#pragma unroll
      for (int r = 0; r < 4; ++r) {
        int lp = g2 * 16 + lhi * 4 + r;
        sfh[((kcw * 4 + wv) * 64 + lp) * 8 + eo] = f2bf(hv[r]);
      }
#pragma unroll
      for (int r = 0; r < 4; ++r) {
        int row = wv * 16 + lhi * 4 + r;
        out[(size_t)(t * 64 + row) * 256 + colg] = hv[r];
        if (t == TT - 1) out[(size_t)16777216 + (size_t)row * 256 + colg] = hv[r];
      }
    }
    GBAR(t * 7 + 6);
  }
#undef GBAR
#undef LOADA
#undef MM
#undef UPD
#undef STOREF
}

extern "C" void kernel_launch(void* const* d_in, const int* in_sizes, int n_in,
                              void* d_out, int out_size, void* d_ws, size_t ws_size,
                              hipStream_t stream) {
  const float* x   = (const float*)d_in[0];   // [1024,64,256] f32
  const float* hid = (const float*)d_in[1];   // [1,64,256] f32
  const float* W0  = (const float*)d_in[2];   // [512,512] f32
  const float* Ws  = (const float*)d_in[3];   // [8,256,512] f32
  float* out = (float*)d_out;                 // [1024*64*256 + 64*256] f32
  unsigned short* sf = (unsigned short*)d_ws; // 7 frag buffers x 16384 bf16
  unsigned* cnt = (unsigned*)((char*)d_ws + 7 * 32768);  // 7168 barrier counters

  hipFuncSetAttribute((const void*)darts_main,
                      hipFuncAttributeMaxDynamicSharedMemorySize, 131072);
  darts_init<<<8, 256, 0, stream>>>(hid, sf, cnt);
  darts_main<<<NWG, 256, 131072, stream>>>(x, hid, W0, Ws, out, sf, cnt);
}